// Round 5
// baseline (70.511 us; speedup 1.0000x reference)
//
#include <hip/hip_runtime.h>
#include <math.h>

typedef short bfx8 __attribute__((ext_vector_type(8)));
typedef short bfx4 __attribute__((ext_vector_type(4)));
typedef float fx4  __attribute__((ext_vector_type(4)));

__device__ __forceinline__ unsigned short f2bf(float f) {
    unsigned int u = __builtin_bit_cast(unsigned int, f);
    u += 0x7FFFu + ((u >> 16) & 1u);        // round-to-nearest-even
    return (unsigned short)(u >> 16);
}

__device__ __forceinline__ short2 pk_bf16(float a, float b) {
    // compiler fuses the two RNE roundings into v_cvt_pk_bf16_f32 where possible
    short2 r;
    r.x = (short)f2bf(a);
    r.y = (short)f2bf(b);
    return r;
}

// ---------- Wt prep: wt[192][1024] bf16 = [Wq*(2^-5*log2e); Wk; Wv]^T ----------
__global__ __launch_bounds__(256) void wt_prep(const float* __restrict__ Wq,
                                               const float* __restrict__ Wk,
                                               const float* __restrict__ Wv,
                                               unsigned short* __restrict__ wt)
{
    const int k0  = blockIdx.x * 64;
    const int mat = blockIdx.y;
    const float* W = (mat == 0) ? Wq : ((mat == 1) ? Wk : Wv);
    // fold softmax scale AND log2(e) into Wq -> scores come out in base-2 domain
    const float scale = (mat == 0) ? (0.03125f * 1.4426950408889634f) : 1.0f;
    __shared__ unsigned short Ls[64 * 68];
    const int t = threadIdx.x;
    #pragma unroll
    for (int i = 0; i < 4; ++i) {
        int idx4 = t + 256 * i;
        int r = idx4 >> 4, c4 = idx4 & 15;
        float4 v = *(const float4*)&W[(size_t)(k0 + r) * 64 + c4 * 4];
        Ls[r * 68 + c4 * 4 + 0] = f2bf(v.x * scale);
        Ls[r * 68 + c4 * 4 + 1] = f2bf(v.y * scale);
        Ls[r * 68 + c4 * 4 + 2] = f2bf(v.z * scale);
        Ls[r * 68 + c4 * 4 + 3] = f2bf(v.w * scale);
    }
    __syncthreads();
    #pragma unroll
    for (int i = 0; i < 2; ++i) {
        int u = t + 256 * i;
        int n = u >> 3, kc = u & 7;
        bfx8 o;
        #pragma unroll
        for (int j = 0; j < 8; ++j) o[j] = (short)Ls[(kc * 8 + j) * 68 + n];
        *(bfx8*)&wt[(size_t)(mat * 64 + n) * 1024 + k0 + kc * 8] = o;
    }
}

// ---------- QKV: BM=32, grid 512 (8 waves/CU), MFMA bf16, double-buffered ----------
__global__ __launch_bounds__(256) void qkv_mfma(
    const float* __restrict__ x, const unsigned short* __restrict__ wt,
    unsigned short* __restrict__ qb, unsigned short* __restrict__ kb,
    unsigned short* __restrict__ vt)
{
    __shared__ alignas(16) char smem[57344];  // X bufs @0,4096 (4KB); W bufs @8192,32768 (24KB)
    const int t = threadIdx.x;
    const int w = t >> 6, l = t & 63, g = l >> 4, li = l & 15;
    const int m0 = blockIdx.x * 32;
    const int rh  = (w & 1) * 16;             // row half
    const int nb0 = (w >> 1) * 6;             // n-block base (6 of 12)

    fx4 acc[6];
    #pragma unroll
    for (int i = 0; i < 6; ++i) acc[i] = (fx4){0.f, 0.f, 0.f, 0.f};

    float4 xr[2]; bfx8 wr[6];

#define QKV_LOAD(K0) do { \
    _Pragma("unroll") for (int i_ = 0; i_ < 2; ++i_) { int idx4 = t + 256 * i_; int r_ = idx4 >> 4, c4 = idx4 & 15; \
        xr[i_] = *(const float4*)&x[(size_t)(m0 + r_) * 1024 + (K0) + c4 * 4]; } \
    _Pragma("unroll") for (int i_ = 0; i_ < 6; ++i_) { int idx = t + 256 * i_; int n_ = idx >> 3, c_ = idx & 7; \
        wr[i_] = *(const bfx8*)&wt[(size_t)n_ * 1024 + (K0) + c_ * 8]; } \
} while (0)

#define QKV_STORE(BI) do { \
    char* xb_ = smem + (BI) * 4096; \
    char* wb_ = smem + 8192 + (BI) * 24576; \
    _Pragma("unroll") for (int i_ = 0; i_ < 2; ++i_) { int idx4 = t + 256 * i_; int r_ = idx4 >> 4, c4 = idx4 & 15; \
        short2 lo_ = pk_bf16(xr[i_].x, xr[i_].y), hi_ = pk_bf16(xr[i_].z, xr[i_].w); \
        bfx4 o_; o_[0] = lo_.x; o_[1] = lo_.y; o_[2] = hi_.x; o_[3] = hi_.y; \
        *(bfx4*)(xb_ + ((r_ * 128 + c4 * 8) ^ ((r_ & 7) << 4))) = o_; } \
    _Pragma("unroll") for (int i_ = 0; i_ < 6; ++i_) { int idx = t + 256 * i_; int n_ = idx >> 3, c_ = idx & 7; \
        *(bfx8*)(wb_ + ((n_ * 128 + c_ * 16) ^ ((n_ & 7) << 4))) = wr[i_]; } \
} while (0)

    QKV_LOAD(0); QKV_STORE(0);
    __syncthreads();

    for (int ch = 0; ch < 16; ++ch) {
        if (ch + 1 < 16) QKV_LOAD((ch + 1) * 64);
        if (ch) __syncthreads();
        char* xb = smem + (ch & 1) * 4096;
        char* wb = smem + 8192 + (ch & 1) * 24576;
        const int arow = rh + li;
        #pragma unroll
        for (int kk = 0; kk < 2; ++kk) {
            bfx8 af = *(bfx8*)(xb + ((arow * 128 + kk * 64 + g * 16) ^ ((arow & 7) << 4)));
            #pragma unroll
            for (int nb = 0; nb < 6; ++nb) {
                int nrow = (nb0 + nb) * 16 + li;
                bfx8 bf = *(bfx8*)(wb + ((nrow * 128 + kk * 64 + g * 16) ^ ((nrow & 7) << 4)));
                acc[nb] = __builtin_amdgcn_mfma_f32_16x16x32_bf16(af, bf, acc[nb], 0, 0, 0);
            }
        }
        if (ch + 1 < 16) QKV_STORE((ch + 1) & 1);
    }

    const int mrow = m0 + rh + g * 4;         // D: row=(l>>4)*4+r, col=l&15
    #pragma unroll
    for (int nb = 0; nb < 6; ++nb) {
        const int nbg = nb0 + nb;
        if (nbg < 4) {
            #pragma unroll
            for (int r = 0; r < 4; ++r)
                qb[(size_t)(mrow + r) * 64 + nbg * 16 + li] = f2bf(acc[nb][r]);
        } else if (nbg < 8) {
            #pragma unroll
            for (int r = 0; r < 4; ++r)
                kb[(size_t)(mrow + r) * 64 + (nbg - 4) * 16 + li] = f2bf(acc[nb][r]);
        }
    }

    __syncthreads();                           // reuse smem for V transpose
    unsigned short* Vt = (unsigned short*)smem;      // [64 d][40] (padded)
    #pragma unroll
    for (int nb = 0; nb < 6; ++nb) {
        const int nbg = nb0 + nb;
        if (nbg >= 8) {
            #pragma unroll
            for (int r = 0; r < 4; ++r)
                Vt[((nbg - 8) * 16 + li) * 40 + rh + g * 4 + r] = f2bf(acc[nb][r]);
        }
    }
    __syncthreads();
    const int bb = m0 >> 12, mt = m0 & 4095;
    {
        int d = t >> 2, c = t & 3;             // 64 d x 4 col-groups (8 each) = 256 units
        *(bfx8*)&vt[((size_t)(bb * 64 + d)) * 4096 + mt + c * 8] = *(bfx8*)&Vt[d * 40 + c * 8];
    }
}

// ---------- MFMA flash attention: 2-deep pipeline, base-2 softmax ----------
// grid 512 (b fastest, long q-tiles first), block 256 (4 waves: qsub=w&1, par=w>>1).
__global__ __launch_bounds__(256) void attn_mfma(
    const unsigned short* __restrict__ qb, const unsigned short* __restrict__ kb,
    const unsigned short* __restrict__ vt, float* __restrict__ out)
{
    __shared__ alignas(16) char smem[69632]; // Q @0 (4KB); Kbufs @4096,20480; Vbufs @36864,53248 (16KB each)
    const int t = threadIdx.x;
    const int w = t >> 6, l = t & 63, g = l >> 4, li = l & 15;
    const int bx = blockIdx.x;
    const int b  = bx & 3;
    const int qt = 127 - (bx >> 2);
    const int qbase = qt * 32;
    const int qsub = w & 1, par = w >> 1;

    const unsigned short* Qg = qb + (size_t)b * 4096 * 64;
    const unsigned short* Kg = kb + (size_t)b * 4096 * 64;
    const unsigned short* Vg = vt + (size_t)b * 64 * 4096;
    const int nch = (qbase + 32 + 127) >> 7;

    bfx8 krg[4], vrg[4];

#define ATT_LOAD_K(CB) do { \
    _Pragma("unroll") for (int i_ = 0; i_ < 4; ++i_) { int idx = t + 256 * i_; int r_ = idx >> 3, c_ = idx & 7; \
        krg[i_] = *(const bfx8*)&Kg[(size_t)((CB) + r_) * 64 + c_ * 8]; } \
} while (0)
#define ATT_LOAD_V(CB) do { \
    _Pragma("unroll") for (int i_ = 0; i_ < 4; ++i_) { int idx = t + 256 * i_; int d_ = idx >> 4, c_ = idx & 15; \
        vrg[i_] = *(const bfx8*)&Vg[(size_t)d_ * 4096 + (CB) + c_ * 8]; } \
} while (0)
#define ATT_STORE_K(BI) do { \
    char* kb_ = smem + 4096 + (BI) * 16384; \
    _Pragma("unroll") for (int i_ = 0; i_ < 4; ++i_) { int idx = t + 256 * i_; int r_ = idx >> 3, c_ = idx & 7; \
        *(bfx8*)(kb_ + ((r_ * 128 + c_ * 16) ^ ((r_ & 7) << 4))) = krg[i_]; } \
} while (0)
#define ATT_STORE_V(BI) do { \
    char* vb_ = smem + 36864 + (BI) * 16384; \
    _Pragma("unroll") for (int i_ = 0; i_ < 4; ++i_) { int idx = t + 256 * i_; int d_ = idx >> 4, c_ = idx & 15; \
        *(bfx8*)(vb_ + ((d_ * 256 + c_ * 16) ^ ((d_ & 7) << 4))) = vrg[i_]; } \
} while (0)

    {   // stage Q tile [32][64]
        int r2 = t >> 3, c2 = t & 7;
        bfx8 qv = *(const bfx8*)&Qg[(size_t)(qbase + r2) * 64 + c2 * 8];
        *(bfx8*)(smem + ((r2 * 128 + c2 * 16) ^ ((r2 & 7) << 4))) = qv;
    }
    ATT_LOAD_K(0); ATT_LOAD_V(0);
    ATT_STORE_K(0); ATT_STORE_V(0);
    if (nch > 1) { ATT_LOAD_K(128); ATT_STORE_K(1); }
    __syncthreads();

    const int qrow  = qsub * 16 + li;
    const int qglob = qbase + qrow;
    const int qmin  = qbase + qsub * 16;
    const int qmaxr = qmin + 15;
    const bfx8 qf0 = *(bfx8*)(smem + ((qrow * 128 + g * 16)      ^ ((qrow & 7) << 4)));
    const bfx8 qf1 = *(bfx8*)(smem + ((qrow * 128 + 64 + g * 16) ^ ((qrow & 7) << 4)));

    fx4 o[4];
    #pragma unroll
    for (int i = 0; i < 4; ++i) o[i] = (fx4){0.f, 0.f, 0.f, 0.f};
    float m = -1e30f, lsum = 0.f;
    fx4 sA[4], sB[4];
    #pragma unroll
    for (int i = 0; i < 4; ++i) { sA[i] = (fx4){0.f,0.f,0.f,0.f}; sB[i] = (fx4){0.f,0.f,0.f,0.f}; }

#define QKT(SN, KSB) do { \
    SN[0] = SN[1] = SN[2] = SN[3] = (fx4){0.f, 0.f, 0.f, 0.f}; \
    __builtin_amdgcn_s_setprio(1); \
    _Pragma("unroll") for (int st_ = 0; st_ < 4; ++st_) { \
        int krow_ = par * 64 + st_ * 16 + li; int sw_ = (krow_ & 7) << 4; \
        bfx8 kf0_ = *(bfx8*)((KSB) + ((krow_ * 128 + g * 16) ^ sw_)); \
        bfx8 kf1_ = *(bfx8*)((KSB) + ((krow_ * 128 + 64 + g * 16) ^ sw_)); \
        SN[st_] = __builtin_amdgcn_mfma_f32_16x16x32_bf16(kf0_, qf0, SN[st_], 0, 0, 0); \
        SN[st_] = __builtin_amdgcn_mfma_f32_16x16x32_bf16(kf1_, qf1, SN[st_], 0, 0, 0); } \
    __builtin_amdgcn_s_setprio(0); \
} while (0)

#define BODY(CUR, NXT, CH) do { \
    const int cb_ = (CH) << 7; \
    const bool ldK_ = (CH) + 2 < nch; \
    const bool ldV_ = (CH) + 1 < nch; \
    if (ldK_) ATT_LOAD_K(cb_ + 256); \
    if (ldV_) ATT_LOAD_V(cb_ + 128); \
    if (((CH) + 1 < nch) && (cb_ + 128 + par * 64 <= qmaxr)) \
        QKT(NXT, smem + 4096 + ((((CH) + 1) & 1) * 16384)); \
    if (cb_ + par * 64 <= qmaxr) { \
        const int sub_ = cb_ + par * 64; \
        float p[16]; \
        if (sub_ + 63 > qmin) {  /* diagonal chunk: mask */ \
            _Pragma("unroll") for (int st_ = 0; st_ < 4; ++st_) \
            _Pragma("unroll") for (int rr_ = 0; rr_ < 4; ++rr_) { \
                int kv_ = sub_ + st_ * 16 + 4 * g + rr_; \
                p[st_ * 4 + rr_] = (kv_ <= qglob) ? CUR[st_][rr_] : -1e30f; } \
        } else { \
            _Pragma("unroll") for (int st_ = 0; st_ < 4; ++st_) \
            _Pragma("unroll") for (int rr_ = 0; rr_ < 4; ++rr_) \
                p[st_ * 4 + rr_] = CUR[st_][rr_]; \
        } \
        float x0_ = fmaxf(fmaxf(p[0], p[1]),  fmaxf(p[2], p[3])); \
        float x1_ = fmaxf(fmaxf(p[4], p[5]),  fmaxf(p[6], p[7])); \
        float x2_ = fmaxf(fmaxf(p[8], p[9]),  fmaxf(p[10], p[11])); \
        float x3_ = fmaxf(fmaxf(p[12], p[13]), fmaxf(p[14], p[15])); \
        float pmax_ = fmaxf(fmaxf(x0_, x1_), fmaxf(x2_, x3_)); \
        pmax_ = fmaxf(pmax_, __shfl_xor(pmax_, 16)); \
        pmax_ = fmaxf(pmax_, __shfl_xor(pmax_, 32)); \
        if (__any(pmax_ > m + 8.f)) {  /* defer-max, base-2 */ \
            float mnew_ = fmaxf(m, pmax_); \
            float fac_ = exp2f(m - mnew_); \
            m = mnew_; lsum *= fac_; \
            _Pragma("unroll") for (int d2_ = 0; d2_ < 4; ++d2_) { \
                o[d2_][0] *= fac_; o[d2_][1] *= fac_; o[d2_][2] *= fac_; o[d2_][3] *= fac_; } } \
        _Pragma("unroll") for (int e_ = 0; e_ < 16; ++e_) p[e_] = exp2f(p[e_] - m); \
        lsum += (((p[0]+p[1])+(p[2]+p[3])) + ((p[4]+p[5])+(p[6]+p[7]))) \
              + (((p[8]+p[9])+(p[10]+p[11])) + ((p[12]+p[13])+(p[14]+p[15]))); \
        bfx8 pf0_, pf1_; \
        _Pragma("unroll") for (int i_ = 0; i_ < 4; ++i_) { \
            short2 a_ = pk_bf16(p[2*i_], p[2*i_+1]);       pf0_[2*i_] = a_.x; pf0_[2*i_+1] = a_.y; \
            short2 b_ = pk_bf16(p[8+2*i_], p[8+2*i_+1]);   pf1_[2*i_] = b_.x; pf1_[2*i_+1] = b_.y; } \
        char* vs_ = smem + 36864 + (((CH) & 1) * 16384); \
        __builtin_amdgcn_s_setprio(1); \
        _Pragma("unroll") for (int dblk_ = 0; dblk_ < 4; ++dblk_) { \
            int dr_ = dblk_ * 16 + li; int base_ = dr_ * 256 + par * 128; int sw_ = (dr_ & 7) << 4; \
            bfx4 a0_ = *(bfx4*)(vs_ + ((base_ + 8 * g) ^ sw_)); \
            bfx4 a1_ = *(bfx4*)(vs_ + ((base_ + 32 + 8 * g) ^ sw_)); \
            bfx8 vf_; vf_[0]=a0_[0]; vf_[1]=a0_[1]; vf_[2]=a0_[2]; vf_[3]=a0_[3]; \
                      vf_[4]=a1_[0]; vf_[5]=a1_[1]; vf_[6]=a1_[2]; vf_[7]=a1_[3]; \
            o[dblk_] = __builtin_amdgcn_mfma_f32_16x16x32_bf16(vf_, pf0_, o[dblk_], 0, 0, 0); \
            bfx4 b0_ = *(bfx4*)(vs_ + ((base_ + 64 + 8 * g) ^ sw_)); \
            bfx4 b1_ = *(bfx4*)(vs_ + ((base_ + 96 + 8 * g) ^ sw_)); \
            bfx8 vg_; vg_[0]=b0_[0]; vg_[1]=b0_[1]; vg_[2]=b0_[2]; vg_[3]=b0_[3]; \
                      vg_[4]=b1_[0]; vg_[5]=b1_[1]; vg_[6]=b1_[2]; vg_[7]=b1_[3]; \
            o[dblk_] = __builtin_amdgcn_mfma_f32_16x16x32_bf16(vg_, pf1_, o[dblk_], 0, 0, 0); } \
        __builtin_amdgcn_s_setprio(0); \
    } \
    if (ldK_) ATT_STORE_K((CH) & 1); \
    if (ldV_) ATT_STORE_V(((CH) + 1) & 1); \
    __syncthreads(); \
} while (0)

    // prologue: compute S(0) into sA, then publish-protect with a barrier
    if (par * 64 <= qmaxr) QKT(sA, smem + 4096);
    __syncthreads();

    int ch = 0;
    for (; ch + 1 < nch; ch += 2) {
        BODY(sA, sB, ch);
        BODY(sB, sA, ch + 1);
    }
    if (ch < nch) BODY(sA, sB, ch);

    // ---- 2-way merge (wave w with w+2); lsum partials summed here ----
    float* Osh = (float*)(smem + 4096);              // [4 waves][16 q][64 d]
    float* msh = (float*)smem;                       // [4][16] m
    float* lsh = (float*)(smem + 1024);              // [4 waves][4 g][16] lsum partials
    #pragma unroll
    for (int dblk = 0; dblk < 4; ++dblk)
        #pragma unroll
        for (int r = 0; r < 4; ++r)
            Osh[(w * 16 + li) * 64 + dblk * 16 + g * 4 + r] = o[dblk][r];
    if (g == 0) msh[w * 16 + li] = m;
    lsh[(w * 4 + g) * 16 + li] = lsum;
    __syncthreads();

    const int q = t >> 3, dc = (t & 7) * 8;
    const int ql = q & 15, qs2 = q >> 4;
    const int wA = qs2, wB = qs2 + 2;
    const float mA = msh[wA * 16 + ql], mB = msh[wB * 16 + ql];
    const float lA = lsh[(wA * 4 + 0) * 16 + ql] + lsh[(wA * 4 + 1) * 16 + ql]
                   + lsh[(wA * 4 + 2) * 16 + ql] + lsh[(wA * 4 + 3) * 16 + ql];
    const float lB = lsh[(wB * 4 + 0) * 16 + ql] + lsh[(wB * 4 + 1) * 16 + ql]
                   + lsh[(wB * 4 + 2) * 16 + ql] + lsh[(wB * 4 + 3) * 16 + ql];
    const float M  = fmaxf(mA, mB);
    const float eA = exp2f(mA - M), eB = exp2f(mB - M);
    const float inv = 1.f / (lA * eA + lB * eB);
    float* orow = out + ((size_t)b * 4096 + qbase + q) * 64 + dc;
    const float* OA = &Osh[(wA * 16 + ql) * 64 + dc];
    const float* OB = &Osh[(wB * 16 + ql) * 64 + dc];
    float4 ra0 = *(const float4*)&OA[0], ra1 = *(const float4*)&OA[4];
    float4 rb0 = *(const float4*)&OB[0], rb1 = *(const float4*)&OB[4];
    float4 r0, r1;
    r0.x = (ra0.x * eA + rb0.x * eB) * inv; r0.y = (ra0.y * eA + rb0.y * eB) * inv;
    r0.z = (ra0.z * eA + rb0.z * eB) * inv; r0.w = (ra0.w * eA + rb0.w * eB) * inv;
    r1.x = (ra1.x * eA + rb1.x * eB) * inv; r1.y = (ra1.y * eA + rb1.y * eB) * inv;
    r1.z = (ra1.z * eA + rb1.z * eB) * inv; r1.w = (ra1.w * eA + rb1.w * eB) * inv;
    *(float4*)&orow[0] = r0;
    *(float4*)&orow[4] = r1;
}

extern "C" void kernel_launch(void* const* d_in, const int* in_sizes, int n_in,
                              void* d_out, int out_size, void* d_ws, size_t ws_size,
                              hipStream_t stream)
{
    // setup_inputs order: x, Wk, Wq, Wv
    const float* x  = (const float*)d_in[0];
    const float* Wk = (const float*)d_in[1];
    const float* Wq = (const float*)d_in[2];
    const float* Wv = (const float*)d_in[3];
    float* outp = (float*)d_out;

    unsigned short* qbuf = (unsigned short*)d_ws;        // [4][4096][64] bf16 (pre-scaled, base-2)
    unsigned short* kbuf = qbuf + (1u << 20);            // [4][4096][64] bf16
    unsigned short* vtb  = kbuf + (1u << 20);            // [4][64][4096] bf16 (V^T)
    unsigned short* wtb  = vtb  + (1u << 20);            // [192][1024] bf16 (W^T)

    wt_prep<<<dim3(16, 3), 256, 0, stream>>>(Wq, Wk, Wv, wtb);
    qkv_mfma<<<512, 256, 0, stream>>>(x, wtb, qbuf, kbuf, vtb);
    attn_mfma<<<512, 256, 0, stream>>>(qbuf, kbuf, vtb, outp);
}

// Round 6
// 70.469 us; speedup vs baseline: 1.0006x; 1.0006x over previous
//
#include <hip/hip_runtime.h>
#include <math.h>

typedef short bfx8 __attribute__((ext_vector_type(8)));
typedef short bfx4 __attribute__((ext_vector_type(4)));
typedef float fx4  __attribute__((ext_vector_type(4)));

__device__ __forceinline__ unsigned short f2bf(float f) {
    unsigned int u = __builtin_bit_cast(unsigned int, f);
    u += 0x7FFFu + ((u >> 16) & 1u);        // round-to-nearest-even
    return (unsigned short)(u >> 16);
}

__device__ __forceinline__ short2 pk_bf16(float a, float b) {
    // compiler fuses the two RNE roundings into v_cvt_pk_bf16_f32 where possible
    short2 r;
    r.x = (short)f2bf(a);
    r.y = (short)f2bf(b);
    return r;
}

// ---------- Wt prep: wt[192][1024] bf16 = [Wq*(2^-5*log2e); Wk; Wv]^T ----------
__global__ __launch_bounds__(256) void wt_prep(const float* __restrict__ Wq,
                                               const float* __restrict__ Wk,
                                               const float* __restrict__ Wv,
                                               unsigned short* __restrict__ wt)
{
    const int k0  = blockIdx.x * 64;
    const int mat = blockIdx.y;
    const float* W = (mat == 0) ? Wq : ((mat == 1) ? Wk : Wv);
    // fold softmax scale AND log2(e) into Wq -> scores come out in base-2 domain
    const float scale = (mat == 0) ? (0.03125f * 1.4426950408889634f) : 1.0f;
    __shared__ unsigned short Ls[64 * 68];
    const int t = threadIdx.x;
    #pragma unroll
    for (int i = 0; i < 4; ++i) {
        int idx4 = t + 256 * i;
        int r = idx4 >> 4, c4 = idx4 & 15;
        float4 v = *(const float4*)&W[(size_t)(k0 + r) * 64 + c4 * 4];
        Ls[r * 68 + c4 * 4 + 0] = f2bf(v.x * scale);
        Ls[r * 68 + c4 * 4 + 1] = f2bf(v.y * scale);
        Ls[r * 68 + c4 * 4 + 2] = f2bf(v.z * scale);
        Ls[r * 68 + c4 * 4 + 3] = f2bf(v.w * scale);
    }
    __syncthreads();
    #pragma unroll
    for (int i = 0; i < 2; ++i) {
        int u = t + 256 * i;
        int n = u >> 3, kc = u & 7;
        bfx8 o;
        #pragma unroll
        for (int j = 0; j < 8; ++j) o[j] = (short)Ls[(kc * 8 + j) * 68 + n];
        *(bfx8*)&wt[(size_t)(mat * 64 + n) * 1024 + k0 + kc * 8] = o;
    }
}

// ---------- QKV: BM=32, grid 512 (8 waves/CU), MFMA bf16, double-buffered ----------
__global__ __launch_bounds__(256) void qkv_mfma(
    const float* __restrict__ x, const unsigned short* __restrict__ wt,
    unsigned short* __restrict__ qb, unsigned short* __restrict__ kb,
    unsigned short* __restrict__ vt)
{
    __shared__ alignas(16) char smem[57344];  // X bufs @0,4096 (4KB); W bufs @8192,32768 (24KB)
    const int t = threadIdx.x;
    const int w = t >> 6, l = t & 63, g = l >> 4, li = l & 15;
    const int m0 = blockIdx.x * 32;
    const int rh  = (w & 1) * 16;             // row half
    const int nb0 = (w >> 1) * 6;             // n-block base (6 of 12)

    fx4 acc[6];
    #pragma unroll
    for (int i = 0; i < 6; ++i) acc[i] = (fx4){0.f, 0.f, 0.f, 0.f};

    float4 xr[2]; bfx8 wr[6];

#define QKV_LOAD(K0) do { \
    _Pragma("unroll") for (int i_ = 0; i_ < 2; ++i_) { int idx4 = t + 256 * i_; int r_ = idx4 >> 4, c4 = idx4 & 15; \
        xr[i_] = *(const float4*)&x[(size_t)(m0 + r_) * 1024 + (K0) + c4 * 4]; } \
    _Pragma("unroll") for (int i_ = 0; i_ < 6; ++i_) { int idx = t + 256 * i_; int n_ = idx >> 3, c_ = idx & 7; \
        wr[i_] = *(const bfx8*)&wt[(size_t)n_ * 1024 + (K0) + c_ * 8]; } \
} while (0)

#define QKV_STORE(BI) do { \
    char* xb_ = smem + (BI) * 4096; \
    char* wb_ = smem + 8192 + (BI) * 24576; \
    _Pragma("unroll") for (int i_ = 0; i_ < 2; ++i_) { int idx4 = t + 256 * i_; int r_ = idx4 >> 4, c4 = idx4 & 15; \
        short2 lo_ = pk_bf16(xr[i_].x, xr[i_].y), hi_ = pk_bf16(xr[i_].z, xr[i_].w); \
        bfx4 o_; o_[0] = lo_.x; o_[1] = lo_.y; o_[2] = hi_.x; o_[3] = hi_.y; \
        *(bfx4*)(xb_ + ((r_ * 128 + c4 * 8) ^ ((r_ & 7) << 4))) = o_; } \
    _Pragma("unroll") for (int i_ = 0; i_ < 6; ++i_) { int idx = t + 256 * i_; int n_ = idx >> 3, c_ = idx & 7; \
        *(bfx8*)(wb_ + ((n_ * 128 + c_ * 16) ^ ((n_ & 7) << 4))) = wr[i_]; } \
} while (0)

    QKV_LOAD(0); QKV_STORE(0);
    __syncthreads();

    for (int ch = 0; ch < 16; ++ch) {
        if (ch + 1 < 16) QKV_LOAD((ch + 1) * 64);
        if (ch) __syncthreads();
        char* xb = smem + (ch & 1) * 4096;
        char* wb = smem + 8192 + (ch & 1) * 24576;
        const int arow = rh + li;
        #pragma unroll
        for (int kk = 0; kk < 2; ++kk) {
            bfx8 af = *(bfx8*)(xb + ((arow * 128 + kk * 64 + g * 16) ^ ((arow & 7) << 4)));
            #pragma unroll
            for (int nb = 0; nb < 6; ++nb) {
                int nrow = (nb0 + nb) * 16 + li;
                bfx8 bf = *(bfx8*)(wb + ((nrow * 128 + kk * 64 + g * 16) ^ ((nrow & 7) << 4)));
                acc[nb] = __builtin_amdgcn_mfma_f32_16x16x32_bf16(af, bf, acc[nb], 0, 0, 0);
            }
        }
        if (ch + 1 < 16) QKV_STORE((ch + 1) & 1);
    }

    const int mrow = m0 + rh + g * 4;         // D: row=(l>>4)*4+r, col=l&15
    #pragma unroll
    for (int nb = 0; nb < 6; ++nb) {
        const int nbg = nb0 + nb;
        if (nbg < 4) {
            #pragma unroll
            for (int r = 0; r < 4; ++r)
                qb[(size_t)(mrow + r) * 64 + nbg * 16 + li] = f2bf(acc[nb][r]);
        } else if (nbg < 8) {
            #pragma unroll
            for (int r = 0; r < 4; ++r)
                kb[(size_t)(mrow + r) * 64 + (nbg - 4) * 16 + li] = f2bf(acc[nb][r]);
        }
    }

    __syncthreads();                           // reuse smem for V transpose
    unsigned short* Vt = (unsigned short*)smem;      // [64 d][40] (padded)
    #pragma unroll
    for (int nb = 0; nb < 6; ++nb) {
        const int nbg = nb0 + nb;
        if (nbg >= 8) {
            #pragma unroll
            for (int r = 0; r < 4; ++r)
                Vt[((nbg - 8) * 16 + li) * 40 + rh + g * 4 + r] = f2bf(acc[nb][r]);
        }
    }
    __syncthreads();
    const int bb = m0 >> 12, mt = m0 & 4095;
    {
        int d = t >> 2, c = t & 3;             // 64 d x 4 col-groups (8 each) = 256 units
        *(bfx8*)&vt[((size_t)(bb * 64 + d)) * 4096 + mt + c * 8] = *(bfx8*)&Vt[d * 40 + c * 8];
    }
}

// ---------- MFMA flash attention: 2-deep pipeline, base-2 softmax ----------
// grid 512 (b fastest, long q-tiles first), block 256 (4 waves: qsub=w&1, par=w>>1).
__global__ __launch_bounds__(256) void attn_mfma(
    const unsigned short* __restrict__ qb, const unsigned short* __restrict__ kb,
    const unsigned short* __restrict__ vt, float* __restrict__ out)
{
    __shared__ alignas(16) char smem[69632]; // Q @0 (4KB); Kbufs @4096,20480; Vbufs @36864,53248 (16KB each)
    const int t = threadIdx.x;
    const int w = t >> 6, l = t & 63, g = l >> 4, li = l & 15;
    const int bx = blockIdx.x;
    const int b  = bx & 3;
    const int qt = 127 - (bx >> 2);
    const int qbase = qt * 32;
    const int qsub = w & 1, par = w >> 1;

    const unsigned short* Qg = qb + (size_t)b * 4096 * 64;
    const unsigned short* Kg = kb + (size_t)b * 4096 * 64;
    const unsigned short* Vg = vt + (size_t)b * 64 * 4096;
    const int nch = (qbase + 32 + 127) >> 7;

    bfx8 krg[4], vrg[4];

#define ATT_LOAD_K(CB) do { \
    _Pragma("unroll") for (int i_ = 0; i_ < 4; ++i_) { int idx = t + 256 * i_; int r_ = idx >> 3, c_ = idx & 7; \
        krg[i_] = *(const bfx8*)&Kg[(size_t)((CB) + r_) * 64 + c_ * 8]; } \
} while (0)
#define ATT_LOAD_V(CB) do { \
    _Pragma("unroll") for (int i_ = 0; i_ < 4; ++i_) { int idx = t + 256 * i_; int d_ = idx >> 4, c_ = idx & 15; \
        vrg[i_] = *(const bfx8*)&Vg[(size_t)d_ * 4096 + (CB) + c_ * 8]; } \
} while (0)
#define ATT_STORE_K(BI) do { \
    char* kb_ = smem + 4096 + (BI) * 16384; \
    _Pragma("unroll") for (int i_ = 0; i_ < 4; ++i_) { int idx = t + 256 * i_; int r_ = idx >> 3, c_ = idx & 7; \
        *(bfx8*)(kb_ + ((r_ * 128 + c_ * 16) ^ ((r_ & 7) << 4))) = krg[i_]; } \
} while (0)
#define ATT_STORE_V(BI) do { \
    char* vb_ = smem + 36864 + (BI) * 16384; \
    _Pragma("unroll") for (int i_ = 0; i_ < 4; ++i_) { int idx = t + 256 * i_; int d_ = idx >> 4, c_ = idx & 15; \
        *(bfx8*)(vb_ + ((d_ * 256 + c_ * 16) ^ ((d_ & 7) << 4))) = vrg[i_]; } \
} while (0)

    {   // stage Q tile [32][64]
        int r2 = t >> 3, c2 = t & 7;
        bfx8 qv = *(const bfx8*)&Qg[(size_t)(qbase + r2) * 64 + c2 * 8];
        *(bfx8*)(smem + ((r2 * 128 + c2 * 16) ^ ((r2 & 7) << 4))) = qv;
    }
    ATT_LOAD_K(0); ATT_LOAD_V(0);
    ATT_STORE_K(0); ATT_STORE_V(0);
    if (nch > 1) { ATT_LOAD_K(128); ATT_STORE_K(1); }
    __syncthreads();

    const int qrow  = qsub * 16 + li;
    const int qglob = qbase + qrow;
    const int qmin  = qbase + qsub * 16;
    const int qmaxr = qmin + 15;
    const bfx8 qf0 = *(bfx8*)(smem + ((qrow * 128 + g * 16)      ^ ((qrow & 7) << 4)));
    const bfx8 qf1 = *(bfx8*)(smem + ((qrow * 128 + 64 + g * 16) ^ ((qrow & 7) << 4)));

    fx4 o[4];
    #pragma unroll
    for (int i = 0; i < 4; ++i) o[i] = (fx4){0.f, 0.f, 0.f, 0.f};
    float m = -1e30f, lsum = 0.f;
    fx4 sA[4], sB[4];
    #pragma unroll
    for (int i = 0; i < 4; ++i) { sA[i] = (fx4){0.f,0.f,0.f,0.f}; sB[i] = (fx4){0.f,0.f,0.f,0.f}; }

#define QKT(SN, KSB) do { \
    SN[0] = SN[1] = SN[2] = SN[3] = (fx4){0.f, 0.f, 0.f, 0.f}; \
    __builtin_amdgcn_s_setprio(1); \
    _Pragma("unroll") for (int st_ = 0; st_ < 4; ++st_) { \
        int krow_ = par * 64 + st_ * 16 + li; int sw_ = (krow_ & 7) << 4; \
        bfx8 kf0_ = *(bfx8*)((KSB) + ((krow_ * 128 + g * 16) ^ sw_)); \
        bfx8 kf1_ = *(bfx8*)((KSB) + ((krow_ * 128 + 64 + g * 16) ^ sw_)); \
        SN[st_] = __builtin_amdgcn_mfma_f32_16x16x32_bf16(kf0_, qf0, SN[st_], 0, 0, 0); \
        SN[st_] = __builtin_amdgcn_mfma_f32_16x16x32_bf16(kf1_, qf1, SN[st_], 0, 0, 0); } \
    __builtin_amdgcn_s_setprio(0); \
} while (0)

#define BODY(CUR, NXT, CH) do { \
    const int cb_ = (CH) << 7; \
    const bool ldK_ = (CH) + 2 < nch; \
    const bool ldV_ = (CH) + 1 < nch; \
    if (ldK_) ATT_LOAD_K(cb_ + 256); \
    if (ldV_) ATT_LOAD_V(cb_ + 128); \
    if (((CH) + 1 < nch) && (cb_ + 128 + par * 64 <= qmaxr)) \
        QKT(NXT, smem + 4096 + ((((CH) + 1) & 1) * 16384)); \
    if (cb_ + par * 64 <= qmaxr) { \
        const int sub_ = cb_ + par * 64; \
        float p[16]; \
        if (sub_ + 63 > qmin) {  /* diagonal chunk: mask */ \
            _Pragma("unroll") for (int st_ = 0; st_ < 4; ++st_) \
            _Pragma("unroll") for (int rr_ = 0; rr_ < 4; ++rr_) { \
                int kv_ = sub_ + st_ * 16 + 4 * g + rr_; \
                p[st_ * 4 + rr_] = (kv_ <= qglob) ? CUR[st_][rr_] : -1e30f; } \
        } else { \
            _Pragma("unroll") for (int st_ = 0; st_ < 4; ++st_) \
            _Pragma("unroll") for (int rr_ = 0; rr_ < 4; ++rr_) \
                p[st_ * 4 + rr_] = CUR[st_][rr_]; \
        } \
        float x0_ = fmaxf(fmaxf(p[0], p[1]),  fmaxf(p[2], p[3])); \
        float x1_ = fmaxf(fmaxf(p[4], p[5]),  fmaxf(p[6], p[7])); \
        float x2_ = fmaxf(fmaxf(p[8], p[9]),  fmaxf(p[10], p[11])); \
        float x3_ = fmaxf(fmaxf(p[12], p[13]), fmaxf(p[14], p[15])); \
        float pmax_ = fmaxf(fmaxf(x0_, x1_), fmaxf(x2_, x3_)); \
        pmax_ = fmaxf(pmax_, __shfl_xor(pmax_, 16)); \
        pmax_ = fmaxf(pmax_, __shfl_xor(pmax_, 32)); \
        if (__any(pmax_ > m + 8.f)) {  /* defer-max, base-2 */ \
            float mnew_ = fmaxf(m, pmax_); \
            float fac_ = exp2f(m - mnew_); \
            m = mnew_; lsum *= fac_; \
            _Pragma("unroll") for (int d2_ = 0; d2_ < 4; ++d2_) { \
                o[d2_][0] *= fac_; o[d2_][1] *= fac_; o[d2_][2] *= fac_; o[d2_][3] *= fac_; } } \
        _Pragma("unroll") for (int e_ = 0; e_ < 16; ++e_) p[e_] = exp2f(p[e_] - m); \
        lsum += (((p[0]+p[1])+(p[2]+p[3])) + ((p[4]+p[5])+(p[6]+p[7]))) \
              + (((p[8]+p[9])+(p[10]+p[11])) + ((p[12]+p[13])+(p[14]+p[15]))); \
        bfx8 pf0_, pf1_; \
        _Pragma("unroll") for (int i_ = 0; i_ < 4; ++i_) { \
            short2 a_ = pk_bf16(p[2*i_], p[2*i_+1]);       pf0_[2*i_] = a_.x; pf0_[2*i_+1] = a_.y; \
            short2 b_ = pk_bf16(p[8+2*i_], p[8+2*i_+1]);   pf1_[2*i_] = b_.x; pf1_[2*i_+1] = b_.y; } \
        char* vs_ = smem + 36864 + (((CH) & 1) * 16384); \
        __builtin_amdgcn_s_setprio(1); \
        _Pragma("unroll") for (int dblk_ = 0; dblk_ < 4; ++dblk_) { \
            int dr_ = dblk_ * 16 + li; int base_ = dr_ * 256 + par * 128; int sw_ = (dr_ & 7) << 4; \
            bfx4 a0_ = *(bfx4*)(vs_ + ((base_ + 8 * g) ^ sw_)); \
            bfx4 a1_ = *(bfx4*)(vs_ + ((base_ + 32 + 8 * g) ^ sw_)); \
            bfx8 vf_; vf_[0]=a0_[0]; vf_[1]=a0_[1]; vf_[2]=a0_[2]; vf_[3]=a0_[3]; \
                      vf_[4]=a1_[0]; vf_[5]=a1_[1]; vf_[6]=a1_[2]; vf_[7]=a1_[3]; \
            o[dblk_] = __builtin_amdgcn_mfma_f32_16x16x32_bf16(vf_, pf0_, o[dblk_], 0, 0, 0); \
            bfx4 b0_ = *(bfx4*)(vs_ + ((base_ + 64 + 8 * g) ^ sw_)); \
            bfx4 b1_ = *(bfx4*)(vs_ + ((base_ + 96 + 8 * g) ^ sw_)); \
            bfx8 vg_; vg_[0]=b0_[0]; vg_[1]=b0_[1]; vg_[2]=b0_[2]; vg_[3]=b0_[3]; \
                      vg_[4]=b1_[0]; vg_[5]=b1_[1]; vg_[6]=b1_[2]; vg_[7]=b1_[3]; \
            o[dblk_] = __builtin_amdgcn_mfma_f32_16x16x32_bf16(vg_, pf1_, o[dblk_], 0, 0, 0); } \
        __builtin_amdgcn_s_setprio(0); \
    } \
    if (ldK_) ATT_STORE_K((CH) & 1); \
    if (ldV_) ATT_STORE_V(((CH) + 1) & 1); \
    __syncthreads(); \
} while (0)

    // prologue: compute S(0) into sA, then publish-protect with a barrier
    if (par * 64 <= qmaxr) QKT(sA, smem + 4096);
    __syncthreads();

    int ch = 0;
    for (; ch + 1 < nch; ch += 2) {
        BODY(sA, sB, ch);
        BODY(sB, sA, ch + 1);
    }
    if (ch < nch) BODY(sA, sB, ch);

    // ---- 2-way merge (wave w with w+2); lsum partials summed here ----
    float* Osh = (float*)(smem + 4096);              // [4 waves][16 q][64 d]
    float* msh = (float*)smem;                       // [4][16] m
    float* lsh = (float*)(smem + 1024);              // [4 waves][4 g][16] lsum partials
    #pragma unroll
    for (int dblk = 0; dblk < 4; ++dblk)
        #pragma unroll
        for (int r = 0; r < 4; ++r)
            Osh[(w * 16 + li) * 64 + dblk * 16 + g * 4 + r] = o[dblk][r];
    if (g == 0) msh[w * 16 + li] = m;
    lsh[(w * 4 + g) * 16 + li] = lsum;
    __syncthreads();

    const int q = t >> 3, dc = (t & 7) * 8;
    const int ql = q & 15, qs2 = q >> 4;
    const int wA = qs2, wB = qs2 + 2;
    const float mA = msh[wA * 16 + ql], mB = msh[wB * 16 + ql];
    const float lA = lsh[(wA * 4 + 0) * 16 + ql] + lsh[(wA * 4 + 1) * 16 + ql]
                   + lsh[(wA * 4 + 2) * 16 + ql] + lsh[(wA * 4 + 3) * 16 + ql];
    const float lB = lsh[(wB * 4 + 0) * 16 + ql] + lsh[(wB * 4 + 1) * 16 + ql]
                   + lsh[(wB * 4 + 2) * 16 + ql] + lsh[(wB * 4 + 3) * 16 + ql];
    const float M  = fmaxf(mA, mB);
    const float eA = exp2f(mA - M), eB = exp2f(mB - M);
    const float inv = 1.f / (lA * eA + lB * eB);
    float* orow = out + ((size_t)b * 4096 + qbase + q) * 64 + dc;
    const float* OA = &Osh[(wA * 16 + ql) * 64 + dc];
    const float* OB = &Osh[(wB * 16 + ql) * 64 + dc];
    float4 ra0 = *(const float4*)&OA[0], ra1 = *(const float4*)&OA[4];
    float4 rb0 = *(const float4*)&OB[0], rb1 = *(const float4*)&OB[4];
    float4 r0, r1;
    r0.x = (ra0.x * eA + rb0.x * eB) * inv; r0.y = (ra0.y * eA + rb0.y * eB) * inv;
    r0.z = (ra0.z * eA + rb0.z * eB) * inv; r0.w = (ra0.w * eA + rb0.w * eB) * inv;
    r1.x = (ra1.x * eA + rb1.x * eB) * inv; r1.y = (ra1.y * eA + rb1.y * eB) * inv;
    r1.z = (ra1.z * eA + rb1.z * eB) * inv; r1.w = (ra1.w * eA + rb1.w * eB) * inv;
    *(float4*)&orow[0] = r0;
    *(float4*)&orow[4] = r1;
}

extern "C" void kernel_launch(void* const* d_in, const int* in_sizes, int n_in,
                              void* d_out, int out_size, void* d_ws, size_t ws_size,
                              hipStream_t stream)
{
    // setup_inputs order: x, Wk, Wq, Wv
    const float* x  = (const float*)d_in[0];
    const float* Wk = (const float*)d_in[1];
    const float* Wq = (const float*)d_in[2];
    const float* Wv = (const float*)d_in[3];
    float* outp = (float*)d_out;

    unsigned short* qbuf = (unsigned short*)d_ws;        // [4][4096][64] bf16 (pre-scaled, base-2)
    unsigned short* kbuf = qbuf + (1u << 20);            // [4][4096][64] bf16
    unsigned short* vtb  = kbuf + (1u << 20);            // [4][64][4096] bf16 (V^T)
    unsigned short* wtb  = vtb  + (1u << 20);            // [192][1024] bf16 (W^T)

    wt_prep<<<dim3(16, 3), 256, 0, stream>>>(Wq, Wk, Wv, wtb);
    qkv_mfma<<<512, 256, 0, stream>>>(x, wtb, qbuf, kbuf, vtb);
    attn_mfma<<<512, 256, 0, stream>>>(qbuf, kbuf, vtb, outp);
}